// Round 2
// baseline (204.809 us; speedup 1.0000x reference)
//
#include <hip/hip_runtime.h>
#include <stdint.h>

#define BATCH 4096
#define N_IN  512
#define H1    1536
#define H2    1536
#define N_OUT 512
#define FAN   32
#define E0 (H1 * FAN)
#define E1 (H2 * FAN)
#define E2 (N_OUT * FAN)
#define ETOT (E0 + E1 + E2)
#define MAXDEG 128   // degree clamp (Poisson mean 32; replay-safety)

// ---- workspace layout (bytes) ----
// nvT   (bf16 rows, global node id 0..3583; mask allows reads to 4095): 4096*4096*2 = 33,554,432
// outT  (fp32, 512 x 4096)                                            :  8,388,608
// edges (int2: src, w-bits), CSR-sorted, 3 levels packed              :    917,504
// row_ptr (1537 + 1537 + 513 ints)
#define OFF_OUTT   33554432
#define OFF_EDGES  (OFF_OUTT + 8388608)
#define OFF_RP     (OFF_EDGES + 917504)

__device__ __forceinline__ uint32_t f2bf(float f) {
    uint32_t u = __float_as_uint(f);
    return (u + 0x7fffu + ((u >> 16) & 1u)) >> 16;   // RNE bf16
}

// ---------- x [B, N_IN] fp32 -> xT [N_IN, B] bf16 (rows 0..511 of nvT) ----------
__global__ __launch_bounds__(256) void k_transpose_in(const float* __restrict__ x,
                                                      uint16_t* __restrict__ xT) {
    __shared__ float tile[32][33];
    const int tx = threadIdx.x, ty = threadIdx.y;   // 32 x 8
    const int n0 = blockIdx.x * 32;                 // node base
    const int b0 = blockIdx.y * 32;                 // batch base
#pragma unroll
    for (int k = 0; k < 32; k += 8)
        tile[ty + k][tx] = x[(size_t)(b0 + ty + k) * N_IN + (n0 + tx)];
    __syncthreads();
#pragma unroll
    for (int k = 0; k < 32; k += 8)
        xT[(size_t)(n0 + ty + k) * BATCH + (b0 + tx)] = (uint16_t)f2bf(tile[tx][ty + k]);
}

// ---------- merged CSR build: one block per level (zero+count+scan+fill in LDS) ----------
__global__ __launch_bounds__(1024) void k_csr(const int* __restrict__ s0, const int* __restrict__ d0, const float* __restrict__ w0,
                                              const int* __restrict__ s1, const int* __restrict__ d1, const float* __restrict__ w1,
                                              const int* __restrict__ s2, const int* __restrict__ d2, const float* __restrict__ w2,
                                              int* __restrict__ row_ptr, int2* __restrict__ edges) {
    const int lvl = blockIdx.x;
    const int n     = (lvl == 2) ? N_OUT : H1;
    const int E     = (lvl == 0) ? E0 : (lvl == 1) ? E1 : E2;
    const int ebase = (lvl == 0) ? 0 : (lvl == 1) ? E0 : (E0 + E1);
    const int rbase = (lvl == 0) ? 0 : (lvl == 1) ? (H1 + 1) : (H1 + 1 + H2 + 1);
    const int* __restrict__ src = (lvl == 0) ? s0 : (lvl == 1) ? s1 : s2;
    const int* __restrict__ dst = (lvl == 0) ? d0 : (lvl == 1) ? d1 : d2;
    const float* __restrict__ w = (lvl == 0) ? w0 : (lvl == 1) ? w1 : w2;

    __shared__ int cnt_s[H1];     // counters, then cursors
    __shared__ int ssum[256];
    const int t = threadIdx.x;

    for (int i = t; i < n; i += 1024) cnt_s[i] = 0;
    __syncthreads();
    for (int e = t; e < E; e += 1024) atomicAdd(&cnt_s[dst[e]], 1);
    __syncthreads();

    const int chunk = n / 256;                      // 6, 6, 2 — exact
    int local[6];
    if (t < 256) {
        int sum = 0;
        for (int j = 0; j < chunk; ++j) { local[j] = cnt_s[t * chunk + j]; sum += local[j]; }
        ssum[t] = sum;
    }
    __syncthreads();
    for (int off = 1; off < 256; off <<= 1) {
        int v = (t >= off && t < 256) ? ssum[t - off] : 0;
        __syncthreads();
        if (t < 256) ssum[t] += v;
        __syncthreads();
    }
    if (t < 256) {
        int base = (t == 0) ? 0 : ssum[t - 1];
        for (int j = 0; j < chunk; ++j) {
            row_ptr[rbase + t * chunk + j] = base;
            cnt_s[t * chunk + j] = base;            // becomes cursor
            base += local[j];
        }
        if (t == 255) row_ptr[rbase + n] = base;
    }
    __syncthreads();
    for (int e = t; e < E; e += 1024) {
        const int d = dst[e];
        const int pos = atomicAdd(&cnt_s[d], 1);
        edges[ebase + pos] = make_int2(src[e], __float_as_int(w[e]));
    }
}

// ---------- level kernel: one node per block, 4 col-tiles, 8 cols/thread (16B gathers) ----------
template <bool FP32OUT>
__global__ __launch_bounds__(128)
void k_level(const int2* __restrict__ edges,
             const int* __restrict__ row_ptr,
             const uint4* __restrict__ nv,        // nvT as uint4 rows (512 uint4 per row)
             uint4* __restrict__ outb,            // bf16 out rows (pre-offset), levels 0/1
             float* __restrict__ outf) {          // fp32 out, level 2
    __shared__ int2 eds[MAXDEG];
    const int node = blockIdx.y;
    const int tid  = threadIdx.x;
    const int col8 = (blockIdx.x << 7) | tid;     // uint4 index within a 512-uint4 row

    const int begin = row_ptr[node];
    int cnt = row_ptr[node + 1] - begin;
    cnt = (cnt < 0) ? 0 : (cnt > MAXDEG ? MAXDEG : cnt);
    if (tid < cnt) eds[tid] = edges[begin + tid];
    __syncthreads();

    float a0 = 0.f, a1 = 0.f, a2 = 0.f, a3 = 0.f, a4 = 0.f, a5 = 0.f, a6 = 0.f, a7 = 0.f;

#define ACC8(q, W)                                                     \
    a0 = fmaf(__uint_as_float((q).x << 16),          (W), a0);         \
    a1 = fmaf(__uint_as_float((q).x & 0xffff0000u),  (W), a1);         \
    a2 = fmaf(__uint_as_float((q).y << 16),          (W), a2);         \
    a3 = fmaf(__uint_as_float((q).y & 0xffff0000u),  (W), a3);         \
    a4 = fmaf(__uint_as_float((q).z << 16),          (W), a4);         \
    a5 = fmaf(__uint_as_float((q).z & 0xffff0000u),  (W), a5);         \
    a6 = fmaf(__uint_as_float((q).w << 16),          (W), a6);         \
    a7 = fmaf(__uint_as_float((q).w & 0xffff0000u),  (W), a7);

    int j = 0;
    for (; j + 2 <= cnt; j += 2) {
        const int2 e0 = eds[j];
        const int2 e1 = eds[j + 1];
        const int s0i = __builtin_amdgcn_readfirstlane(e0.x & 4095);
        const int s1i = __builtin_amdgcn_readfirstlane(e1.x & 4095);
        const float wa = __int_as_float(__builtin_amdgcn_readfirstlane(e0.y));
        const float wb = __int_as_float(__builtin_amdgcn_readfirstlane(e1.y));
        const uint4 q0 = nv[((size_t)s0i << 9) | col8];
        const uint4 q1 = nv[((size_t)s1i << 9) | col8];
        ACC8(q0, wa);
        ACC8(q1, wb);
    }
    if (j < cnt) {
        const int2 e0 = eds[j];
        const int s0i = __builtin_amdgcn_readfirstlane(e0.x & 4095);
        const float wa = __int_as_float(__builtin_amdgcn_readfirstlane(e0.y));
        const uint4 q0 = nv[((size_t)s0i << 9) | col8];
        ACC8(q0, wa);
    }
#undef ACC8

    a0 = fmaxf(a0, 0.f); a1 = fmaxf(a1, 0.f); a2 = fmaxf(a2, 0.f); a3 = fmaxf(a3, 0.f);
    a4 = fmaxf(a4, 0.f); a5 = fmaxf(a5, 0.f); a6 = fmaxf(a6, 0.f); a7 = fmaxf(a7, 0.f);

    if (FP32OUT) {
        float* p = outf + (((size_t)node << 12) | ((size_t)col8 << 3));
        float4 r0; r0.x = a0; r0.y = a1; r0.z = a2; r0.w = a3;
        float4 r1; r1.x = a4; r1.y = a5; r1.z = a6; r1.w = a7;
        *(float4*)p = r0;
        *(float4*)(p + 4) = r1;
    } else {
        uint4 p;
        p.x = f2bf(a0) | (f2bf(a1) << 16);
        p.y = f2bf(a2) | (f2bf(a3) << 16);
        p.z = f2bf(a4) | (f2bf(a5) << 16);
        p.w = f2bf(a6) | (f2bf(a7) << 16);
        outb[((size_t)node << 9) | col8] = p;
    }
}

// ---------- outT [N_OUT, B] fp32 -> out [B, N_OUT] fp32 ----------
__global__ __launch_bounds__(256) void k_transpose_out(const float* __restrict__ outT,
                                                       float* __restrict__ out) {
    __shared__ float tile[32][33];
    const int tx = threadIdx.x, ty = threadIdx.y;   // 32 x 8
    const int n0 = blockIdx.x * 32;
    const int b0 = blockIdx.y * 32;
#pragma unroll
    for (int k = 0; k < 32; k += 8)
        tile[ty + k][tx] = outT[(size_t)(n0 + ty + k) * BATCH + (b0 + tx)];
    __syncthreads();
#pragma unroll
    for (int k = 0; k < 32; k += 8)
        out[(size_t)(b0 + ty + k) * N_OUT + (n0 + tx)] = tile[tx][ty + k];
}

extern "C" void kernel_launch(void* const* d_in, const int* in_sizes, int n_in,
                              void* d_out, int out_size, void* d_ws, size_t ws_size,
                              hipStream_t stream) {
    const float* x  = (const float*)d_in[0];
    const int* s0   = (const int*)d_in[1];
    const int* dd0  = (const int*)d_in[2];
    const float* w0 = (const float*)d_in[3];
    const int* s1   = (const int*)d_in[4];
    const int* dd1  = (const int*)d_in[5];
    const float* w1 = (const float*)d_in[6];
    const int* s2   = (const int*)d_in[7];
    const int* dd2  = (const int*)d_in[8];
    const float* w2 = (const float*)d_in[9];

    char* ws        = (char*)d_ws;
    uint4*    nv4   = (uint4*)ws;                    // nvT bf16, 512 uint4 per node row
    float*    outT  = (float*)(ws + OFF_OUTT);
    int2*     edges = (int2*)(ws + OFF_EDGES);
    int*      rp    = (int*)(ws + OFF_RP);

    // CSR build (one kernel, replay-idempotent)
    k_csr<<<3, 1024, 0, stream>>>(s0, dd0, w0, s1, dd1, w1, s2, dd2, w2, rp, edges);

    // x -> bf16 transposed node-value rows 0..511
    k_transpose_in<<<dim3(N_IN / 32, BATCH / 32), dim3(32, 8), 0, stream>>>(x, (uint16_t*)ws);

    // levels: grid (4 col-tiles, H nodes), 128 threads, 8 cols/thread
    k_level<false><<<dim3(4, H1), 128, 0, stream>>>(edges, rp, nv4,
                                                    nv4 + (size_t)N_IN * 512, nullptr);
    k_level<false><<<dim3(4, H2), 128, 0, stream>>>(edges + E0, rp + (H1 + 1), nv4,
                                                    nv4 + (size_t)(N_IN + H1) * 512, nullptr);
    k_level<true><<<dim3(4, N_OUT), 128, 0, stream>>>(edges + E0 + E1, rp + (H1 + 1 + H2 + 1), nv4,
                                                      nullptr, outT);

    // outT -> d_out [B, N_OUT]
    k_transpose_out<<<dim3(N_OUT / 32, BATCH / 32), dim3(32, 8), 0, stream>>>(outT, (float*)d_out);
}

// Round 3
// 151.093 us; speedup vs baseline: 1.3555x; 1.3555x over previous
//
#include <hip/hip_runtime.h>
#include <hip/hip_fp16.h>
#include <stdint.h>

#define BATCH 4096
#define N_IN  512
#define H1    1536
#define H2    1536
#define N_OUT 512
#define FAN   32
#define E0 (H1 * FAN)
#define E1 (H2 * FAN)
#define E2 (N_OUT * FAN)
#define ETOT (E0 + E1 + E2)
#define NNODES (H1 + H2 + N_OUT)   // 3584 non-input nodes
#define MAXDEG 96                  // Poisson(32) max over 3584 nodes ~54; 96 is safe

// ---- workspace layout (bytes), total 36,321,280 < 38.7 MB proven in R1 ----
// nv    : 4096 rows x 4096 cols x 2B = 33,554,432
//         rows 0..511  = x^T (bf16), rows 512..2047 = h1 (bf16),
//         rows 2048..3583 = h2 (bf16), rows 3584..4095 = out^T (fp16)
// edges : slotted [NNODES][MAXDEG] int2 = 2,752,512
// cnt   : NNODES ints = 14,336
#define OFF_EDGES 33554432
#define OFF_CNT   (OFF_EDGES + NNODES * MAXDEG * 8)

__device__ __forceinline__ uint32_t f2bf(float f) {
    uint32_t u = __float_as_uint(f);
    return (u + 0x7fffu + ((u >> 16) & 1u)) >> 16;   // RNE bf16
}

// ---------- x [B, N_IN] fp32 -> rows 0..511 of nv (bf16, [node][batch]) ----------
__global__ __launch_bounds__(256) void k_transpose_in(const float* __restrict__ x,
                                                      uint16_t* __restrict__ xT) {
    __shared__ float tile[32][33];
    const int tx = threadIdx.x, ty = threadIdx.y;   // 32 x 8
    const int n0 = blockIdx.x * 32;                 // node base
    const int b0 = blockIdx.y * 32;                 // batch base
#pragma unroll
    for (int k = 0; k < 32; k += 8)
        tile[ty + k][tx] = x[(size_t)(b0 + ty + k) * N_IN + (n0 + tx)];
    __syncthreads();
#pragma unroll
    for (int k = 0; k < 32; k += 8)
        xT[(size_t)(n0 + ty + k) * BATCH + (b0 + tx)] = (uint16_t)f2bf(tile[tx][ty + k]);
}

// ---------- slotted edge-table fill: one pass, no scan ----------
__global__ __launch_bounds__(256) void k_fill(const int* __restrict__ s0, const int* __restrict__ d0, const float* __restrict__ w0,
                                              const int* __restrict__ s1, const int* __restrict__ d1, const float* __restrict__ w1,
                                              const int* __restrict__ s2, const int* __restrict__ d2, const float* __restrict__ w2,
                                              int* __restrict__ cnt, int2* __restrict__ edges) {
    const int e = blockIdx.x * 256 + threadIdx.x;
    int src, node; float w;
    if (e < E0)           { src = s0[e];          node = d0[e];                w = w0[e]; }
    else if (e < E0 + E1) { int i = e - E0;       src = s1[i]; node = H1 + d1[i];        w = w1[i]; }
    else                  { int i = e - E0 - E1;  src = s2[i]; node = H1 + H2 + d2[i];   w = w2[i]; }
    const int pos = atomicAdd(&cnt[node], 1);
    if (pos < MAXDEG) edges[node * MAXDEG + pos] = make_int2(src, __float_as_int(w));
}

// ---------- level kernel: 1-wave blocks, grid (8 col-tiles, H nodes) ----------
// XCD pinning: linear block id = 8*node + tile -> tile t lands on XCD t under %8
// round-robin; per-XCD gather footprint = prev_nodes*512*2B <= 3.67 MB (fits 4 MB L2).
template <bool FP16OUT>
__global__ __launch_bounds__(64)
void k_level(const int2* __restrict__ edges,   // pre-offset: level base * MAXDEG
             const int* __restrict__ cnt,      // pre-offset: level node base
             const uint4* __restrict__ nv,     // 512 uint4 per node row
             uint4* __restrict__ outb) {       // pre-offset row base (uint4 units)
    __shared__ int2 eds[MAXDEG];
    const int node = blockIdx.y;
    const int tid  = threadIdx.x;
    const int col8 = (blockIdx.x << 6) | tid;  // uint4 index, 0..511

    int c = cnt[node];
    c = (c < 0) ? 0 : (c > MAXDEG ? MAXDEG : c);
    for (int i = tid; i < c; i += 64) eds[i] = edges[node * MAXDEG + i];
    __syncthreads();

    float a0 = 0.f, a1 = 0.f, a2 = 0.f, a3 = 0.f, a4 = 0.f, a5 = 0.f, a6 = 0.f, a7 = 0.f;

#define ACC8(q, W)                                                     \
    a0 = fmaf(__uint_as_float((q).x << 16),          (W), a0);         \
    a1 = fmaf(__uint_as_float((q).x & 0xffff0000u),  (W), a1);         \
    a2 = fmaf(__uint_as_float((q).y << 16),          (W), a2);         \
    a3 = fmaf(__uint_as_float((q).y & 0xffff0000u),  (W), a3);         \
    a4 = fmaf(__uint_as_float((q).z << 16),          (W), a4);         \
    a5 = fmaf(__uint_as_float((q).z & 0xffff0000u),  (W), a5);         \
    a6 = fmaf(__uint_as_float((q).w << 16),          (W), a6);         \
    a7 = fmaf(__uint_as_float((q).w & 0xffff0000u),  (W), a7);

    int j = 0;
    for (; j + 2 <= c; j += 2) {
        const int2 e0 = eds[j];
        const int2 e1 = eds[j + 1];
        const int s0i = __builtin_amdgcn_readfirstlane(e0.x & 4095);
        const int s1i = __builtin_amdgcn_readfirstlane(e1.x & 4095);
        const float wa = __int_as_float(__builtin_amdgcn_readfirstlane(e0.y));
        const float wb = __int_as_float(__builtin_amdgcn_readfirstlane(e1.y));
        const uint4 q0 = nv[((size_t)s0i << 9) | col8];
        const uint4 q1 = nv[((size_t)s1i << 9) | col8];
        ACC8(q0, wa);
        ACC8(q1, wb);
    }
    if (j < c) {
        const int2 e0 = eds[j];
        const int s0i = __builtin_amdgcn_readfirstlane(e0.x & 4095);
        const float wa = __int_as_float(__builtin_amdgcn_readfirstlane(e0.y));
        const uint4 q0 = nv[((size_t)s0i << 9) | col8];
        ACC8(q0, wa);
    }
#undef ACC8

    a0 = fmaxf(a0, 0.f); a1 = fmaxf(a1, 0.f); a2 = fmaxf(a2, 0.f); a3 = fmaxf(a3, 0.f);
    a4 = fmaxf(a4, 0.f); a5 = fmaxf(a5, 0.f); a6 = fmaxf(a6, 0.f); a7 = fmaxf(a7, 0.f);

    uint4 p;
    if (FP16OUT) {
        __half2 h0 = __floats2half2_rn(a0, a1);
        __half2 h1 = __floats2half2_rn(a2, a3);
        __half2 h2 = __floats2half2_rn(a4, a5);
        __half2 h3 = __floats2half2_rn(a6, a7);
        p.x = *(uint32_t*)&h0; p.y = *(uint32_t*)&h1;
        p.z = *(uint32_t*)&h2; p.w = *(uint32_t*)&h3;
    } else {
        p.x = f2bf(a0) | (f2bf(a1) << 16);
        p.y = f2bf(a2) | (f2bf(a3) << 16);
        p.z = f2bf(a4) | (f2bf(a5) << 16);
        p.w = f2bf(a6) | (f2bf(a7) << 16);
    }
    outb[((size_t)node << 9) | col8] = p;
}

// ---------- out^T rows (fp16, [N_OUT][B]) -> d_out [B, N_OUT] fp32 ----------
__global__ __launch_bounds__(256) void k_transpose_out(const __half* __restrict__ outh,
                                                       float* __restrict__ out) {
    __shared__ float tile[32][33];
    const int tx = threadIdx.x, ty = threadIdx.y;   // 32 x 8
    const int n0 = blockIdx.x * 32;
    const int b0 = blockIdx.y * 32;
#pragma unroll
    for (int k = 0; k < 32; k += 8)
        tile[ty + k][tx] = __half2float(outh[(size_t)(n0 + ty + k) * BATCH + (b0 + tx)]);
    __syncthreads();
#pragma unroll
    for (int k = 0; k < 32; k += 8)
        out[(size_t)(b0 + ty + k) * N_OUT + (n0 + tx)] = tile[tx][ty + k];
}

extern "C" void kernel_launch(void* const* d_in, const int* in_sizes, int n_in,
                              void* d_out, int out_size, void* d_ws, size_t ws_size,
                              hipStream_t stream) {
    const float* x  = (const float*)d_in[0];
    const int* s0   = (const int*)d_in[1];
    const int* dd0  = (const int*)d_in[2];
    const float* w0 = (const float*)d_in[3];
    const int* s1   = (const int*)d_in[4];
    const int* dd1  = (const int*)d_in[5];
    const float* w1 = (const float*)d_in[6];
    const int* s2   = (const int*)d_in[7];
    const int* dd2  = (const int*)d_in[8];
    const float* w2 = (const float*)d_in[9];

    char* ws        = (char*)d_ws;
    uint4*    nv4   = (uint4*)ws;                    // bf16 node rows, 512 uint4/row
    int2*     edges = (int2*)(ws + OFF_EDGES);
    int*      cnt   = (int*)(ws + OFF_CNT);

    // slotted edge build: memset + one massively-parallel fill (no scan)
    hipMemsetAsync(cnt, 0, NNODES * sizeof(int), stream);
    k_fill<<<ETOT / 256, 256, 0, stream>>>(s0, dd0, w0, s1, dd1, w1, s2, dd2, w2, cnt, edges);

    // x -> bf16 transposed node-value rows 0..511
    k_transpose_in<<<dim3(N_IN / 32, BATCH / 32), dim3(32, 8), 0, stream>>>(x, (uint16_t*)ws);

    // levels: grid (8 col-tiles, H nodes), 64 threads (1 wave), 8 cols/thread
    k_level<false><<<dim3(8, H1), 64, 0, stream>>>(edges, cnt, nv4,
                                                   nv4 + (size_t)N_IN * 512);
    k_level<false><<<dim3(8, H2), 64, 0, stream>>>(edges + (size_t)H1 * MAXDEG, cnt + H1, nv4,
                                                   nv4 + (size_t)(N_IN + H1) * 512);
    k_level<true><<<dim3(8, N_OUT), 64, 0, stream>>>(edges + (size_t)(H1 + H2) * MAXDEG, cnt + H1 + H2, nv4,
                                                     nv4 + (size_t)(N_IN + H1 + H2) * 512);

    // out^T (fp16) -> d_out [B, N_OUT] fp32
    k_transpose_out<<<dim3(N_OUT / 32, BATCH / 32), dim3(32, 8), 0, stream>>>(
        (const __half*)(ws + (size_t)(N_IN + H1 + H2) * BATCH * 2), (float*)d_out);
}

// Round 4
// 146.881 us; speedup vs baseline: 1.3944x; 1.0287x over previous
//
#include <hip/hip_runtime.h>
#include <hip/hip_fp16.h>
#include <stdint.h>

#define BATCH 4096
#define N_IN  512
#define H1    1536
#define H2    1536
#define N_OUT 512
#define FAN   32
#define E0 (H1 * FAN)
#define E1 (H2 * FAN)
#define E2 (N_OUT * FAN)
#define ETOT (E0 + E1 + E2)
#define NNODES (H1 + H2 + N_OUT)   // 3584 non-input nodes
#define MAXDEG 128                 // slot capacity; Poisson(32) max ~54, 128 = guard-free staging

// ---- workspace layout (bytes), total 37,238,784 (< 38.7 MB proven safe in R1) ----
// nv    : 4096 rows x 4096 cols x 2B (fp16) = 33,554,432
//         rows 0..511 = x^T, 512..2047 = h1, 2048..3583 = h2, 3584..4095 = out^T
// edges : slotted [NNODES][MAXDEG] int2 = 3,670,016
// cnt   : NNODES ints = 14,336
#define OFF_EDGES 33554432
#define OFF_CNT   (OFF_EDGES + NNODES * MAXDEG * 8)

// ---------- x [B, N_IN] fp32 -> rows 0..511 of nv (fp16, [node][batch]) ----------
__global__ __launch_bounds__(256) void k_transpose_in(const float* __restrict__ x,
                                                      __half* __restrict__ xT) {
    __shared__ float tile[32][33];
    const int tx = threadIdx.x, ty = threadIdx.y;   // 32 x 8
    const int n0 = blockIdx.x * 32;                 // node base
    const int b0 = blockIdx.y * 32;                 // batch base
#pragma unroll
    for (int k = 0; k < 32; k += 8)
        tile[ty + k][tx] = x[(size_t)(b0 + ty + k) * N_IN + (n0 + tx)];
    __syncthreads();
#pragma unroll
    for (int k = 0; k < 32; k += 8)
        xT[(size_t)(n0 + ty + k) * BATCH + (b0 + tx)] = __float2half_rn(tile[tx][ty + k]);
}

// ---------- slotted edge-table fill: one pass, no scan ----------
__global__ __launch_bounds__(256) void k_fill(const int* __restrict__ s0, const int* __restrict__ d0, const float* __restrict__ w0,
                                              const int* __restrict__ s1, const int* __restrict__ d1, const float* __restrict__ w1,
                                              const int* __restrict__ s2, const int* __restrict__ d2, const float* __restrict__ w2,
                                              int* __restrict__ cnt, int2* __restrict__ edges) {
    const int e = blockIdx.x * 256 + threadIdx.x;
    int src, node; float w;
    if (e < E0)           { src = s0[e];          node = d0[e];                w = w0[e]; }
    else if (e < E0 + E1) { int i = e - E0;       src = s1[i]; node = H1 + d1[i];        w = w1[i]; }
    else                  { int i = e - E0 - E1;  src = s2[i]; node = H1 + H2 + d2[i];   w = w2[i]; }
    const int pos = atomicAdd(&cnt[node], 1);
    if (pos < MAXDEG) edges[node * MAXDEG + pos] = make_int2(src, __float_as_int(w));
}

// ---------- level kernel: 256 thr = 4 waves, wave = one node, 8 col-tiles ----------
// Linear block id = 8*y + x -> tile x pins to XCD x (%8 round-robin heuristic);
// per-XCD gather footprint = prev_nodes * 512 cols * 2B <= 2 MB (fits 4 MB L2).
// Edges staged in VGPRs (lane i holds edge i), read back via readlane — no LDS,
// no __syncthreads, scalar gather base, 4 independent 1KB gathers in flight.
__global__ __launch_bounds__(256)
void k_level(const int2* __restrict__ edges,   // pre-offset: level base * MAXDEG
             const int* __restrict__ cnt,      // pre-offset: level node base
             const uint4* __restrict__ nv,     // 512 uint4 per node row (fp16 x8)
             uint4* __restrict__ outb) {       // pre-offset row base (uint4 units)
    const int lane = threadIdx.x & 63;
    const int wv   = threadIdx.x >> 6;
    const int node = (blockIdx.y << 2) | wv;
    const int col8 = (blockIdx.x << 6) | lane;  // uint4 index in row, 0..511

    int c = cnt[node];
    c = (c < 0) ? 0 : (c > MAXDEG ? MAXDEG : c);

    float a0 = 0.f, a1 = 0.f, a2 = 0.f, a3 = 0.f, a4 = 0.f, a5 = 0.f, a6 = 0.f, a7 = 0.f;

#define ACC8(q, W) {                                                    \
    const __half2 h0 = *(const __half2*)&(q).x;                         \
    const __half2 h1 = *(const __half2*)&(q).y;                         \
    const __half2 h2 = *(const __half2*)&(q).z;                         \
    const __half2 h3 = *(const __half2*)&(q).w;                         \
    a0 = fmaf(__low2float(h0),  (W), a0);                               \
    a1 = fmaf(__high2float(h0), (W), a1);                               \
    a2 = fmaf(__low2float(h1),  (W), a2);                               \
    a3 = fmaf(__high2float(h1), (W), a3);                               \
    a4 = fmaf(__low2float(h2),  (W), a4);                               \
    a5 = fmaf(__high2float(h2), (W), a5);                               \
    a6 = fmaf(__low2float(h3),  (W), a6);                               \
    a7 = fmaf(__high2float(h3), (W), a7); }

    for (int base = 0; base < c; base += 64) {
        // stage up to 64 edges of this wave's node into registers (always in-bounds)
        const int2 my = edges[(size_t)node * MAXDEG + base + lane];
        const int m = (c - base < 64) ? (c - base) : 64;
        int j = 0;
        for (; j + 4 <= m; j += 4) {
            const int   s0i = __builtin_amdgcn_readlane(my.x, j)     & 4095;
            const int   s1i = __builtin_amdgcn_readlane(my.x, j + 1) & 4095;
            const int   s2i = __builtin_amdgcn_readlane(my.x, j + 2) & 4095;
            const int   s3i = __builtin_amdgcn_readlane(my.x, j + 3) & 4095;
            const float wa  = __int_as_float(__builtin_amdgcn_readlane(my.y, j));
            const float wb  = __int_as_float(__builtin_amdgcn_readlane(my.y, j + 1));
            const float wc  = __int_as_float(__builtin_amdgcn_readlane(my.y, j + 2));
            const float wd  = __int_as_float(__builtin_amdgcn_readlane(my.y, j + 3));
            const uint4 q0 = nv[((size_t)s0i << 9) | col8];
            const uint4 q1 = nv[((size_t)s1i << 9) | col8];
            const uint4 q2 = nv[((size_t)s2i << 9) | col8];
            const uint4 q3 = nv[((size_t)s3i << 9) | col8];
            ACC8(q0, wa);
            ACC8(q1, wb);
            ACC8(q2, wc);
            ACC8(q3, wd);
        }
        for (; j < m; ++j) {
            const int   s0i = __builtin_amdgcn_readlane(my.x, j) & 4095;
            const float wa  = __int_as_float(__builtin_amdgcn_readlane(my.y, j));
            const uint4 q0 = nv[((size_t)s0i << 9) | col8];
            ACC8(q0, wa);
        }
    }
#undef ACC8

    a0 = fmaxf(a0, 0.f); a1 = fmaxf(a1, 0.f); a2 = fmaxf(a2, 0.f); a3 = fmaxf(a3, 0.f);
    a4 = fmaxf(a4, 0.f); a5 = fmaxf(a5, 0.f); a6 = fmaxf(a6, 0.f); a7 = fmaxf(a7, 0.f);

    const __half2 h0 = __floats2half2_rn(a0, a1);
    const __half2 h1 = __floats2half2_rn(a2, a3);
    const __half2 h2 = __floats2half2_rn(a4, a5);
    const __half2 h3 = __floats2half2_rn(a6, a7);
    uint4 p;
    p.x = *(const uint32_t*)&h0; p.y = *(const uint32_t*)&h1;
    p.z = *(const uint32_t*)&h2; p.w = *(const uint32_t*)&h3;
    outb[((size_t)node << 9) | col8] = p;
}

// ---------- out^T rows (fp16, [N_OUT][B]) -> d_out [B, N_OUT] fp32 ----------
__global__ __launch_bounds__(256) void k_transpose_out(const __half* __restrict__ outh,
                                                       float* __restrict__ out) {
    __shared__ float tile[32][33];
    const int tx = threadIdx.x, ty = threadIdx.y;   // 32 x 8
    const int n0 = blockIdx.x * 32;
    const int b0 = blockIdx.y * 32;
#pragma unroll
    for (int k = 0; k < 32; k += 8)
        tile[ty + k][tx] = __half2float(outh[(size_t)(n0 + ty + k) * BATCH + (b0 + tx)]);
    __syncthreads();
#pragma unroll
    for (int k = 0; k < 32; k += 8)
        out[(size_t)(b0 + ty + k) * N_OUT + (n0 + tx)] = tile[tx][ty + k];
}

extern "C" void kernel_launch(void* const* d_in, const int* in_sizes, int n_in,
                              void* d_out, int out_size, void* d_ws, size_t ws_size,
                              hipStream_t stream) {
    const float* x  = (const float*)d_in[0];
    const int* s0   = (const int*)d_in[1];
    const int* dd0  = (const int*)d_in[2];
    const float* w0 = (const float*)d_in[3];
    const int* s1   = (const int*)d_in[4];
    const int* dd1  = (const int*)d_in[5];
    const float* w1 = (const float*)d_in[6];
    const int* s2   = (const int*)d_in[7];
    const int* dd2  = (const int*)d_in[8];
    const float* w2 = (const float*)d_in[9];

    char* ws        = (char*)d_ws;
    uint4*    nv4   = (uint4*)ws;                    // fp16 node rows, 512 uint4/row
    int2*     edges = (int2*)(ws + OFF_EDGES);
    int*      cnt   = (int*)(ws + OFF_CNT);

    // slotted edge build: memset + one massively-parallel fill (no scan)
    hipMemsetAsync(cnt, 0, NNODES * sizeof(int), stream);
    k_fill<<<ETOT / 256, 256, 0, stream>>>(s0, dd0, w0, s1, dd1, w1, s2, dd2, w2, cnt, edges);

    // x -> fp16 transposed node-value rows 0..511
    k_transpose_in<<<dim3(N_IN / 32, BATCH / 32), dim3(32, 8), 0, stream>>>(x, (__half*)ws);

    // levels: grid (8 col-tiles, H/4), 256 threads = 4 waves = 4 nodes
    k_level<<<dim3(8, H1 / 4), 256, 0, stream>>>(edges, cnt, nv4,
                                                 nv4 + (size_t)N_IN * 512);
    k_level<<<dim3(8, H2 / 4), 256, 0, stream>>>(edges + (size_t)H1 * MAXDEG, cnt + H1, nv4,
                                                 nv4 + (size_t)(N_IN + H1) * 512);
    k_level<<<dim3(8, N_OUT / 4), 256, 0, stream>>>(edges + (size_t)(H1 + H2) * MAXDEG, cnt + H1 + H2, nv4,
                                                    nv4 + (size_t)(N_IN + H1 + H2) * 512);

    // out^T (fp16) -> d_out [B, N_OUT] fp32
    k_transpose_out<<<dim3(N_OUT / 32, BATCH / 32), dim3(32, 8), 0, stream>>>(
        (const __half*)(ws + (size_t)(N_IN + H1 + H2) * BATCH * 2), (float*)d_out);
}